// Round 1
// baseline (5954.230 us; speedup 1.0000x reference)
//
#include <hip/hip_runtime.h>
#include <math.h>

// LatentDynamics: out[b,t,:] = scan of h' = tanh(h*leak + sigmoid(h@Wh^T + z_t@Wz^T + b)*z_t)
// B=64, T=512, D=1024.
// Phase 0 (k_prep):   fp32->f16 conversion of z and W (split Wh/Wz), h0->f16, zero flags.
// Phase 1 (k_gemm_zw): A[m,j] = sum_k z16[m,k]*Wz16[j,k] + bias[j]  -> written into d_out (fp32).
// Phase 2 (k_recur):  persistent 256-WG kernel; j-partitioned Wh in LDS; per-step h exchange
//                     through a global f16 double buffer with per-WG monotonic flags
//                     (release/acquire at agent scope). A is read from d_out and overwritten
//                     in place with h_{t+1}.

#define D_ 1024
#define B_ 64
#define T_ 512

typedef _Float16 f16;
typedef _Float16 f16x8 __attribute__((ext_vector_type(8)));
typedef _Float16 f16x4 __attribute__((ext_vector_type(4)));
typedef float f32x4 __attribute__((ext_vector_type(4)));

// workspace layout (bytes); total 71,566,336 (~68.3 MB)
#define WS_Z16   0L
#define WS_WH16  67108864L
#define WS_WZ16  69206016L
#define WS_HBUF  71303168L
#define WS_FLAGS 71565312L

__device__ __forceinline__ void gload_lds16(const void* g, void* l) {
  // async global->LDS, 16B per lane; LDS dest = wave-uniform base + lane*16
  __builtin_amdgcn_global_load_lds(
      (const __attribute__((address_space(1))) void*)(g),
      (__attribute__((address_space(3))) void*)(l), 16, 0, 0);
}

// ---------------------------------------------------------------- phase 0
__global__ __launch_bounds__(256) void k_prep(
    const float* __restrict__ z, const float* __restrict__ W,
    const float* __restrict__ h0,
    f16* __restrict__ z16, f16* __restrict__ wh16, f16* __restrict__ wz16,
    f16* __restrict__ hbuf, unsigned* __restrict__ flags) {
  long tid = (long)blockIdx.x * blockDim.x + threadIdx.x;
  if (tid < 256) flags[tid] = 0u;
  const long ZN = (long)B_ * T_ * D_;      // 33,554,432
  const long WN = (long)D_ * 2 * D_;       // 2,097,152
  const long HN = (long)B_ * D_;           // 65,536
  const long tot = (ZN + WN + HN) >> 2;
  const long stride = (long)gridDim.x * blockDim.x;
  for (long i = tid; i < tot; i += stride) {
    long e = i << 2;
    const float* src;
    f16* dst;
    if (e < ZN) {
      src = z + e; dst = z16 + e;
    } else if (e < ZN + WN) {
      long e2 = e - ZN;
      long j = e2 >> 11, c = e2 & 2047;
      src = W + e2;
      dst = (c < D_) ? (wh16 + j * D_ + c) : (wz16 + j * D_ + (c - D_));
    } else {
      long e3 = e - ZN - WN;
      src = h0 + e3; dst = hbuf + e3;      // parity-0 buffer = h_0
    }
    float4 v = *(const float4*)src;
    f16x4 o = {(f16)v.x, (f16)v.y, (f16)v.z, (f16)v.w};
    *(f16x4*)dst = o;
  }
}

// ---------------------------------------------------------------- phase 1
// 128x128 tile, 256 threads (4 waves in 2x2), BK=32, f16 MFMA 16x16x32,
// fragment-linear LDS chunks (conflict-free ds_read_b128, static offsets).
__global__ __launch_bounds__(256) void k_gemm_zw(
    const f16* __restrict__ z16, const f16* __restrict__ wz16,
    const float* __restrict__ bias, float* __restrict__ out) {
  __shared__ f16 ldsA[2][8 * 512];  // [buf][rt(8)][lane(64)*8]
  __shared__ f16 ldsB[2][8 * 512];
  const int tid = threadIdx.x, lane = tid & 63, w = tid >> 6;
  const int r16 = lane & 15, g8 = lane >> 4;
  const int nt = blockIdx.x & 7, mt = blockIdx.x >> 3;
  const long m0 = (long)mt * 128, n0 = (long)nt * 128;
  const f16* gA = z16 + (m0 + r16) * D_ + g8 * 8;
  const f16* gB = wz16 + (n0 + r16) * D_ + g8 * 8;
  const int wr = w >> 1, wc = w & 1;
  f32x4 acc[4][4] = {};

  {
#pragma unroll
    for (int c = 0; c < 2; ++c) {
      int ch = __builtin_amdgcn_readfirstlane(w * 2 + c);
      gload_lds16(gA + (long)ch * 16 * D_, &ldsA[0][ch * 512]);
      gload_lds16(gB + (long)ch * 16 * D_, &ldsB[0][ch * 512]);
    }
  }
  __syncthreads();

  for (int ks = 0; ks < 32; ++ks) {
    const int buf = ks & 1;
    if (ks < 31) {
#pragma unroll
      for (int c = 0; c < 2; ++c) {
        int ch = __builtin_amdgcn_readfirstlane(w * 2 + c);
        gload_lds16(gA + (long)ch * 16 * D_ + (ks + 1) * 32, &ldsA[buf ^ 1][ch * 512]);
        gload_lds16(gB + (long)ch * 16 * D_ + (ks + 1) * 32, &ldsB[buf ^ 1][ch * 512]);
      }
    }
    f16x8 af[4], bf[4];
#pragma unroll
    for (int i = 0; i < 4; ++i) af[i] = *(const f16x8*)(&ldsA[buf][(wr * 4 + i) * 512 + lane * 8]);
#pragma unroll
    for (int j = 0; j < 4; ++j) bf[j] = *(const f16x8*)(&ldsB[buf][(wc * 4 + j) * 512 + lane * 8]);
#pragma unroll
    for (int i = 0; i < 4; ++i)
#pragma unroll
      for (int j = 0; j < 4; ++j)
        acc[i][j] = __builtin_amdgcn_mfma_f32_16x16x32_f16(af[i], bf[j], acc[i][j], 0, 0, 0);
    __syncthreads();
  }

  float bj[4];
#pragma unroll
  for (int j = 0; j < 4; ++j) bj[j] = bias[n0 + wc * 64 + j * 16 + r16];
#pragma unroll
  for (int i = 0; i < 4; ++i) {
    const long mb = m0 + wr * 64 + i * 16 + g8 * 4;
#pragma unroll
    for (int j = 0; j < 4; ++j) {
      const long nn = n0 + wc * 64 + j * 16 + r16;
#pragma unroll
      for (int r = 0; r < 4; ++r)
        out[(mb + r) * D_ + nn] = acc[i][j][r] + bj[j];
    }
  }
}

// ---------------------------------------------------------------- phase 2
// 256 WGs x 256 threads. WG -> (gb in 0..3: 16 batch rows, gj in 0..63: 16 j cols).
// Wh slice LDS-resident (32 KB frag-linear). Per step: stage h16 (32 KB) from the
// parity buffer, 4-wave k-split MFMA, LDS reduce (aliased into Hl), fp32 epilogue,
// publish h16 chunk + flag. LDS = exactly 64 KB.
__global__ __launch_bounds__(256) void k_recur(
    const f16* __restrict__ wh16, f16* __restrict__ hbuf,
    unsigned* __restrict__ flags, const float* __restrict__ z,
    const float* __restrict__ h0, const float* __restrict__ alpha,
    float* __restrict__ out) {
  __shared__ f16 Wl[32 * 512];  // 32 KB, persistent
  __shared__ f16 Hl[32 * 512];  // 32 KB, restaged each step; red/tr alias inside
  float* red = (float*)Hl;          // [4][256] f32 = 4 KB
  f16* tr = Hl + 2048;              // 16x16 f16 = 512 B

  const int tid = threadIdx.x, lane = tid & 63, w = tid >> 6;
  const int r16 = lane & 15, g8 = lane >> 4;
  const int p = blockIdx.x;
  // pair blocks p and p+8 (same XCD under round-robin) onto adjacent j-chunks
  const int member = (p >> 3) & 1;
  const int pair = (p & 7) | ((p >> 4) << 3);  // 0..127
  const int gb = pair & 3, mm = pair >> 2;
  const int gj = 2 * mm + member;
  const int j0 = gj * 16, b0 = gb * 16;

  // persistent Wh slice -> LDS (frag-linear: [ks][lane*8])
  const f16* gW = wh16 + (long)(j0 + r16) * D_ + g8 * 8;
#pragma unroll
  for (int rd = 0; rd < 8; ++rd) {
    int ks = __builtin_amdgcn_readfirstlane(rd * 4 + w);
    gload_lds16(gW + ks * 32, &Wl[ks * 512]);
  }

  float hprev[4] = {0.f, 0.f, 0.f, 0.f};
  float lk = 0.f;
  if (w == 0) {
    lk = 1.0f - alpha[j0 + r16];
#pragma unroll
    for (int r = 0; r < 4; ++r)
      hprev[r] = h0[(long)(b0 + g8 * 4 + r) * D_ + j0 + r16];
  }
  __syncthreads();

  f16* const hb0 = hbuf;
  f16* const hb1 = hbuf + (long)B_ * D_;

  for (int t = 0; t < T_; ++t) {
    // wave0 prefetches A (from d_out) and z for the epilogue; wave1 polls flags
    float Ar[4] = {0, 0, 0, 0}, Zr[4] = {0, 0, 0, 0};
    if (w == 0) {
#pragma unroll
      for (int r = 0; r < 4; ++r) {
        const long off = ((long)(b0 + g8 * 4 + r) * T_ + t) * D_ + j0 + r16;
        Ar[r] = out[off];
        Zr[r] = z[off];
      }
    } else if (w == 1) {
      const unsigned tgt = (unsigned)t;
      bool ok = false;
      for (long it = 0; it < (1L << 20) && !ok; ++it) {
        unsigned f0 = __hip_atomic_load(&flags[lane], __ATOMIC_RELAXED, __HIP_MEMORY_SCOPE_AGENT);
        unsigned f1 = __hip_atomic_load(&flags[lane + 64], __ATOMIC_RELAXED, __HIP_MEMORY_SCOPE_AGENT);
        unsigned f2 = __hip_atomic_load(&flags[lane + 128], __ATOMIC_RELAXED, __HIP_MEMORY_SCOPE_AGENT);
        unsigned f3 = __hip_atomic_load(&flags[lane + 192], __ATOMIC_RELAXED, __HIP_MEMORY_SCOPE_AGENT);
        ok = (bool)__all((f0 >= tgt) & (f1 >= tgt) & (f2 >= tgt) & (f3 >= tgt));
      }
      __builtin_amdgcn_fence(__ATOMIC_ACQUIRE, "agent");
    }
    __syncthreads();  // B1: h_t visible to everyone

    // stage h_t (16 rows x 1024) -> Hl, frag-linear
    const f16* gH = ((t & 1) ? hb1 : hb0) + (long)(b0 + r16) * D_ + g8 * 8;
#pragma unroll
    for (int rd = 0; rd < 8; ++rd) {
      int ks = __builtin_amdgcn_readfirstlane(rd * 4 + w);
      gload_lds16(gH + ks * 32, &Hl[ks * 512]);
    }
    __syncthreads();  // B2: Hl ready

    f32x4 acc = {};
#pragma unroll
    for (int s = 0; s < 8; ++s) {
      const int ks = w * 8 + s;
      f16x8 af = *(const f16x8*)(&Hl[ks * 512 + lane * 8]);
      f16x8 bf = *(const f16x8*)(&Wl[ks * 512 + lane * 8]);
      acc = __builtin_amdgcn_mfma_f32_16x16x32_f16(af, bf, acc, 0, 0, 0);
    }
    __syncthreads();  // B3: all waves done reading Hl (red aliases it)

    *(f32x4*)(red + w * 256 + lane * 4) = acc;
    __syncthreads();  // B4: partials visible

    if (w == 0) {
      f32x4 pre = *(const f32x4*)(red + 0 * 256 + lane * 4);
      pre += *(const f32x4*)(red + 1 * 256 + lane * 4);
      pre += *(const f32x4*)(red + 2 * 256 + lane * 4);
      pre += *(const f32x4*)(red + 3 * 256 + lane * 4);
#pragma unroll
      for (int r = 0; r < 4; ++r) {
        const float g = 1.0f / (1.0f + expf(-(pre[r] + Ar[r])));
        const float hn = tanhf(hprev[r] * lk + g * Zr[r]);
        const long off = ((long)(b0 + g8 * 4 + r) * T_ + t) * D_ + j0 + r16;
        out[off] = hn;                       // overwrite A slot in place
        hprev[r] = hn;                       // exact fp32 state (leak path)
        tr[(g8 * 4 + r) * 16 + r16] = (f16)hn;
      }
    }
    __syncthreads();  // B5: tr ready

    if (tid < 128) {  // publish 16 rows x 16 cols f16 as u32 pairs
      const int rr = tid >> 3, cp = tid & 7;
      const unsigned v = *(const unsigned*)(&tr[rr * 16 + cp * 2]);
      f16* dst = ((t & 1) ? hb0 : hb1) + (long)(b0 + rr) * D_ + j0 + cp * 2;
      *(unsigned*)dst = v;
    }
    __syncthreads();  // B6: drain all waves' publish stores (vmcnt(0) at barrier)

    if (tid == 0)
      __hip_atomic_store(&flags[p], (unsigned)(t + 1), __ATOMIC_RELEASE,
                         __HIP_MEMORY_SCOPE_AGENT);
  }
}

// ---------------------------------------------------------------- launcher
extern "C" void kernel_launch(void* const* d_in, const int* in_sizes, int n_in,
                              void* d_out, int out_size, void* d_ws, size_t ws_size,
                              hipStream_t stream) {
  const float* h_t = (const float*)d_in[0];
  const float* z = (const float*)d_in[1];
  const float* W = (const float*)d_in[2];
  const float* bias = (const float*)d_in[3];
  const float* alpha = (const float*)d_in[4];
  float* out = (float*)d_out;
  char* ws = (char*)d_ws;
  f16* z16 = (f16*)(ws + WS_Z16);
  f16* wh16 = (f16*)(ws + WS_WH16);
  f16* wz16 = (f16*)(ws + WS_WZ16);
  f16* hbuf = (f16*)(ws + WS_HBUF);
  unsigned* flags = (unsigned*)(ws + WS_FLAGS);
  // requires ws_size >= 71,566,336 bytes

  k_prep<<<dim3(2048), dim3(256), 0, stream>>>(z, W, h_t, z16, wh16, wz16, hbuf, flags);
  k_gemm_zw<<<dim3(2048), dim3(256), 0, stream>>>(z16, wz16, bias, out);
  k_recur<<<dim3(256), dim3(256), 0, stream>>>(wh16, hbuf, flags, z, h_t, alpha, out);
}

// Round 2
// 2017.659 us; speedup vs baseline: 2.9511x; 2.9511x over previous
//
#include <hip/hip_runtime.h>
#include <math.h>

// LatentDynamics: out[b,t,:] = scan of h' = tanh(h*leak + sigmoid(h@Wh^T + z_t@Wz^T + b)*z_t)
// B=64, T=512, D=1024.
//
// Phase 0 (k_prep):   fp32->f16 W split (Wh/Wz); init exchange slots (parity0 = h0 tag 0,
//                     parity1 = sentinel) -- re-run every launch, so graph replay is clean.
// Phase 1 (k_gemm_zw): A[m,j] = z[m,:]@Wz^T[j,:] + bias[j] -> d_out (fp32, in-place slot for h).
// Phase 2 (k_recur):  128 persistent WGs = 8 groups (8 batches each) x 16 WGs (64 j each).
//                     Wh slice (64x1024 f16 = 128 KB) LDS-resident. Per step, h exchanged via
//                     FENCE-FREE tagged u64 slots ([tag32 | 2xf16]) with relaxed agent-scope
//                     atomics; parity double-buffer + exact tag==t check gives correctness
//                     independent of XCD placement. No barriers/fences between WGs.

#define D_ 1024
#define B_ 64
#define T_ 512

typedef _Float16 f16;
typedef _Float16 f16x8 __attribute__((ext_vector_type(8)));
typedef _Float16 f16x4 __attribute__((ext_vector_type(4)));
typedef float f32x4 __attribute__((ext_vector_type(4)));
typedef unsigned long long u64;

// workspace layout (bytes); total 4,718,592 (4.5 MB)
#define WS_WH16  0L
#define WS_WZ16  2097152L
#define WS_SLOTS 4194304L
// slots: u64[2][64][512]  (parity, batch, j-pair)

__device__ __forceinline__ void gload_lds16(const void* g, void* l) {
  // async global->LDS, 16B per lane; LDS dest = wave-uniform base + lane*16
  __builtin_amdgcn_global_load_lds(
      (const __attribute__((address_space(1))) void*)(g),
      (__attribute__((address_space(3))) void*)(l), 16, 0, 0);
}

// ---------------------------------------------------------------- phase 0
__global__ __launch_bounds__(256) void k_prep(
    const float* __restrict__ W, const float* __restrict__ h0,
    f16* __restrict__ wh16, f16* __restrict__ wz16, u64* __restrict__ slots) {
  const int tid = blockIdx.x * 256 + threadIdx.x;  // grid = 2048*256 = 524288
  {
    // W: 1024 x 2048 f32 = 2,097,152 = 524288 float4, one per thread
    const long e = (long)tid * 4;
    const long j = e >> 11, c = e & 2047;
    float4 v = *(const float4*)(W + e);
    f16x4 o = {(f16)v.x, (f16)v.y, (f16)v.z, (f16)v.w};
    f16* dst = (c < D_) ? (wh16 + j * D_ + c) : (wz16 + j * D_ + (c - D_));
    *(f16x4*)dst = o;
  }
  if (tid < 65536) {
    if (tid < 32768) {  // parity 0 <- h0, tag 0
      const int b = tid >> 9, p = tid & 511;
      f16 fa = (f16)h0[(long)b * D_ + 2 * p];
      f16 fb = (f16)h0[(long)b * D_ + 2 * p + 1];
      unsigned u = (unsigned)*(unsigned short*)&fa |
                   ((unsigned)*(unsigned short*)&fb << 16);
      slots[tid] = (u64)u;  // high 32 = tag 0
    } else {
      slots[tid] = 0xFFFFFFFF00000000ull;  // parity 1 sentinel (never a valid tag)
    }
  }
}

// ---------------------------------------------------------------- phase 1
// 128x128 tile, 4 waves (2x2), BK=32. A reg-staged from fp32 z (convert inline),
// B (Wz f16) via global_load_lds. 2 barriers per K-step.
__global__ __launch_bounds__(256) void k_gemm_zw(
    const float* __restrict__ zf, const f16* __restrict__ wz16,
    const float* __restrict__ bias, float* __restrict__ out) {
  __shared__ f16 ldsA[8 * 512];
  __shared__ f16 ldsB[8 * 512];
  const int tid = threadIdx.x, lane = tid & 63, w = tid >> 6;
  const int r16 = lane & 15, g8 = lane >> 4;
  const int nt = blockIdx.x & 7, mt = blockIdx.x >> 3;
  const long m0 = (long)mt * 128, n0 = (long)nt * 128;
  const int arow = tid >> 1, kh = (tid & 1) * 16;
  const float* gA = zf + (m0 + arow) * D_ + kh;
  const f16* gB = wz16 + (n0 + r16) * D_ + g8 * 8;
  const int wr = w >> 1, wc = w & 1;
  f32x4 acc[4][4] = {};
  float4 ra[4];
#pragma unroll
  for (int q = 0; q < 4; ++q) ra[q] = *(const float4*)(gA + q * 4);

  for (int ks = 0; ks < 32; ++ks) {
    if (ks) __syncthreads();  // lds reads of ks-1 complete
#pragma unroll
    for (int c = 0; c < 2; ++c) {
      const int ch = w * 2 + c;
      gload_lds16(gB + (long)ch * 16 * D_ + ks * 32, &ldsB[ch * 512]);
    }
    {
      const int ch = arow >> 4, lr = arow & 15;
#pragma unroll
      for (int hf = 0; hf < 2; ++hf) {
        float4 x = ra[hf * 2], y = ra[hf * 2 + 1];
        f16x8 v = {(f16)x.x, (f16)x.y, (f16)x.z, (f16)x.w,
                   (f16)y.x, (f16)y.y, (f16)y.z, (f16)y.w};
        const int kk = kh + hf * 8;
        *(f16x8*)(&ldsA[ch * 512 + (lr | ((kk >> 3) << 4)) * 8]) = v;
      }
    }
    __syncthreads();  // A ds_writes + B gload_lds drained by barrier
    if (ks < 31) {
#pragma unroll
      for (int q = 0; q < 4; ++q)
        ra[q] = *(const float4*)(gA + (ks + 1) * 32 + q * 4);
    }
    f16x8 af[4], bf[4];
#pragma unroll
    for (int i = 0; i < 4; ++i)
      af[i] = *(const f16x8*)(&ldsA[(wr * 4 + i) * 512 + lane * 8]);
#pragma unroll
    for (int j = 0; j < 4; ++j)
      bf[j] = *(const f16x8*)(&ldsB[(wc * 4 + j) * 512 + lane * 8]);
#pragma unroll
    for (int i = 0; i < 4; ++i)
#pragma unroll
      for (int j = 0; j < 4; ++j)
        acc[i][j] = __builtin_amdgcn_mfma_f32_16x16x32_f16(af[i], bf[j], acc[i][j], 0, 0, 0);
  }

  float bj[4];
#pragma unroll
  for (int j = 0; j < 4; ++j) bj[j] = bias[n0 + wc * 64 + j * 16 + r16];
#pragma unroll
  for (int i = 0; i < 4; ++i) {
    const long mb = m0 + wr * 64 + i * 16 + g8 * 4;
#pragma unroll
    for (int j = 0; j < 4; ++j) {
      const long nn = n0 + wc * 64 + j * 16 + r16;
#pragma unroll
      for (int r = 0; r < 4; ++r)
        out[(mb + r) * D_ + nn] = acc[i][j][r] + bj[j];
    }
  }
}

// ---------------------------------------------------------------- phase 2
// 128 WGs x 256 threads, 1/CU. group g = blockIdx&7 (batches g*8..+8),
// rank = blockIdx>>3 (j0 = rank*64). Dynamic LDS 144 KB:
//   Wl  f16[4][32][512] = 128 KB  (B-frags: n-tile, k-tile, lane*8)
//   Hl  u32[8][512]     =  16 KB  (slot-linear h tile, XOR-swizzled; red aliases it)
__global__ __launch_bounds__(256) void k_recur(
    const f16* __restrict__ wh16, u64* slots, const float* __restrict__ z,
    const float* __restrict__ h0, const float* __restrict__ alpha,
    float* __restrict__ out) {
  extern __shared__ char smem[];
  f16* Wl = (f16*)smem;
  char* Hb = smem + 131072;
  float* red = (float*)Hb;

  const int tid = threadIdx.x, lane = tid & 63, w = tid >> 6;
  const int r16 = lane & 15, g8 = lane >> 4;
  const int g = blockIdx.x & 7, rk = blockIdx.x >> 3;
  const int j0 = rk * 64, b0 = g * 8;

  // persistent Wh slice: wave w stages n-tile w (rows j0+w*16..+16, all k)
  {
    const f16* gW = wh16 + (long)(j0 + w * 16 + r16) * D_ + g8 * 8;
#pragma unroll
    for (int ks = 0; ks < 32; ++ks)
      gload_lds16(gW + ks * 32, Wl + w * 16384 + ks * 512);
  }

  const int jj = j0 + lane;
  const float lk = 1.0f - alpha[jj];
  float hp0 = h0[(long)(b0 + w) * D_ + jj];
  float hp1 = h0[(long)(b0 + w + 4) * D_ + jj];

  for (int t = 0; t < T_; ++t) {
    const long off0 = ((long)(b0 + w) * T_ + t) * D_ + jj;
    const long off1 = ((long)(b0 + w + 4) * T_ + t) * D_ + jj;
    // prefetch (in flight during poll; consumed in epilogue)
    float A0 = out[off0], A1 = out[off1];
    float Z0 = z[off0], Z1 = z[off1];

    // ---- fence-free tagged poll: 16 coalesced u64 slots per thread ----
    const u64* cur = slots + (long)(t & 1) * 32768 + (long)b0 * 512;
    u64 vv[16];
    unsigned pend = 0xFFFFu;
    for (int guard = 0; pend && guard < (1 << 18); ++guard) {
#pragma unroll
      for (int i = 0; i < 16; ++i)
        if (pend & (1u << i))
          vv[i] = __hip_atomic_load(cur + i * 256 + tid, __ATOMIC_RELAXED,
                                    __HIP_MEMORY_SCOPE_AGENT);
#pragma unroll
      for (int i = 0; i < 16; ++i)
        if ((pend & (1u << i)) && (unsigned)(vv[i] >> 32) == (unsigned)t)
          pend &= ~(1u << i);
    }
    // scatter payloads to Hl (slot-linear, bank-XOR-swizzled)
#pragma unroll
    for (int i = 0; i < 16; ++i) {
      const int s = i * 256 + tid;
      const int lb = s >> 9, p = s & 511;
      *(unsigned*)(Hb + ((lb * 2048 + p * 4) ^ (lb << 4))) = (unsigned)vv[i];
    }
    __syncthreads();  // B1: Hl staged (also drains Wl gload_lds on t=0)

    // ---- MFMA: wave w = k-quarter; 4 n-tiles; rows 8..15 are broadcast dups ----
    f32x4 acc[4] = {{0,0,0,0},{0,0,0,0},{0,0,0,0},{0,0,0,0}};
    const int row = lane & 7;
#pragma unroll
    for (int kt = 0; kt < 8; ++kt) {
      const int k0 = w * 256 + kt * 32 + g8 * 8;
      f16x8 af = *(const f16x8*)(Hb + ((row * 2048 + k0 * 2) ^ (row << 4)));
#pragma unroll
      for (int n = 0; n < 4; ++n) {
        f16x8 bf = *(const f16x8*)(Wl + n * 16384 + (w * 8 + kt) * 512 + lane * 8);
        acc[n] = __builtin_amdgcn_mfma_f32_16x16x32_f16(af, bf, acc[n], 0, 0, 0);
      }
    }
    __syncthreads();  // B2: Hl reads done (red aliases it)

#pragma unroll
    for (int n = 0; n < 4; ++n)
      *(f32x4*)(red + ((w * 4 + n) * 64 + lane) * 4) = acc[n];
    __syncthreads();  // B3: partials visible

    // ---- reduce + epilogue: thread (w, lane) owns (b0+w, jj) and (b0+w+4, jj) ----
    const int nn = lane >> 4, jc = lane & 15;
    float pre0 = 0.f, pre1 = 0.f;
#pragma unroll
    for (int wp = 0; wp < 4; ++wp) {
      pre0 += red[(wp * 4 + nn) * 256 + jc * 4 + w];
      pre1 += red[(wp * 4 + nn) * 256 + (jc + 16) * 4 + w];
    }
    const float gg0 = 1.0f / (1.0f + expf(-(pre0 + A0)));
    const float gg1 = 1.0f / (1.0f + expf(-(pre1 + A1)));
    const float hn0 = tanhf(hp0 * lk + gg0 * Z0);
    const float hn1 = tanhf(hp1 * lk + gg1 * Z1);
    out[off0] = hn0;  // overwrite A slot in place
    out[off1] = hn1;
    hp0 = hn0; hp1 = hn1;

    // ---- publish tagged pairs (even lanes; relaxed agent atomics, no fence) ----
    const float q0 = __shfl_xor(hn0, 1);
    const float q1 = __shfl_xor(hn1, 1);
    if (!(lane & 1)) {
      f16 pa0 = (f16)hn0, pb0 = (f16)q0, pa1 = (f16)hn1, pb1 = (f16)q1;
      const unsigned u0 = (unsigned)*(unsigned short*)&pa0 |
                          ((unsigned)*(unsigned short*)&pb0 << 16);
      const unsigned u1 = (unsigned)*(unsigned short*)&pa1 |
                          ((unsigned)*(unsigned short*)&pb1 << 16);
      const u64 tagw = ((u64)(unsigned)(t + 1)) << 32;
      u64* pub = slots + (long)((t + 1) & 1) * 32768;
      __hip_atomic_store(pub + (long)(b0 + w) * 512 + (jj >> 1), tagw | (u64)u0,
                         __ATOMIC_RELAXED, __HIP_MEMORY_SCOPE_AGENT);
      __hip_atomic_store(pub + (long)(b0 + w + 4) * 512 + (jj >> 1), tagw | (u64)u1,
                         __ATOMIC_RELAXED, __HIP_MEMORY_SCOPE_AGENT);
    }
    __syncthreads();  // B4: red reads done before next step's Hl scatter
  }
}

// ---------------------------------------------------------------- launcher
extern "C" void kernel_launch(void* const* d_in, const int* in_sizes, int n_in,
                              void* d_out, int out_size, void* d_ws, size_t ws_size,
                              hipStream_t stream) {
  const float* h_t = (const float*)d_in[0];
  const float* z = (const float*)d_in[1];
  const float* W = (const float*)d_in[2];
  const float* bias = (const float*)d_in[3];
  const float* alpha = (const float*)d_in[4];
  float* out = (float*)d_out;
  char* ws = (char*)d_ws;
  f16* wh16 = (f16*)(ws + WS_WH16);
  f16* wz16 = (f16*)(ws + WS_WZ16);
  u64* slots = (u64*)(ws + WS_SLOTS);
  // requires ws_size >= 4,718,592 bytes

  (void)hipFuncSetAttribute((const void*)k_recur,
                            hipFuncAttributeMaxDynamicSharedMemorySize, 147456);

  k_prep<<<dim3(2048), dim3(256), 0, stream>>>(W, h_t, wh16, wz16, slots);
  k_gemm_zw<<<dim3(2048), dim3(256), 0, stream>>>(z, wz16, bias, out);
  k_recur<<<dim3(128), dim3(256), 147456, stream>>>(wh16, slots, z, h_t, alpha, out);
}

// Round 4
// 1410.362 us; speedup vs baseline: 4.2218x; 1.4306x over previous
//
#include <hip/hip_runtime.h>
#include <math.h>

// LatentDynamics: out[b,t,:] = scan of h' = tanh(h*leak + sigmoid(h@Wh^T + z_t@Wz^T + b)*z_t)
// B=64, T=512, D=1024.
//
// Phase 0 (k_prep):   fp32->f16 W split (Wh/Wz); init exchange slots (parity0 = h0 tag 0,
//                     parity1 = sentinel) -- re-run every launch, so graph replay is clean.
// Phase 1 (k_gemm_zw): A[m,j] = z[m,:]@Wz^T[j,:] + bias[j] -> d_out (fp32, in-place slot for h).
// Phase 2 (k_recur):  256 persistent WGs = 16 groups (4 batches each) x 16 WGs (64 j each).
//                     Wh slice register-resident (128 VGPR of B-frags per wave). Per step,
//                     h exchanged via fence-free tagged u64 slots ([tag32 | 2xf16], relaxed
//                     agent atomics). Wave w = k-quarter: polls ONLY its 4 producers' slices
//                     (8 u64/lane), stages wave-locally, MFMAs without barrier; 2 barriers
//                     per step total (reduce in/out).

#define D_ 1024
#define B_ 64
#define T_ 512

typedef _Float16 f16;
typedef _Float16 f16x8 __attribute__((ext_vector_type(8)));
typedef _Float16 f16x4 __attribute__((ext_vector_type(4)));
typedef float f32x4 __attribute__((ext_vector_type(4)));
typedef unsigned long long u64;

// workspace layout (bytes); total 4,718,592 (4.5 MB)
#define WS_WH16  0L
#define WS_WZ16  2097152L
#define WS_SLOTS 4194304L
// slots: u64[2][64][512]  (parity, batch, j-pair)

__device__ __forceinline__ void gload_lds16(const void* g, void* l) {
  __builtin_amdgcn_global_load_lds(
      (const __attribute__((address_space(1))) void*)(g),
      (__attribute__((address_space(3))) void*)(l), 16, 0, 0);
}

// ---------------------------------------------------------------- phase 0
__global__ __launch_bounds__(256) void k_prep(
    const float* __restrict__ W, const float* __restrict__ h0,
    f16* __restrict__ wh16, f16* __restrict__ wz16, u64* __restrict__ slots) {
  const int tid = blockIdx.x * 256 + threadIdx.x;  // grid = 2048*256 = 524288
  {
    const long e = (long)tid * 4;
    const long j = e >> 11, c = e & 2047;
    float4 v = *(const float4*)(W + e);
    f16x4 o = {(f16)v.x, (f16)v.y, (f16)v.z, (f16)v.w};
    f16* dst = (c < D_) ? (wh16 + j * D_ + c) : (wz16 + j * D_ + (c - D_));
    *(f16x4*)dst = o;
  }
  if (tid < 65536) {
    if (tid < 32768) {  // parity 0 <- h0, tag 0
      const int b = tid >> 9, p = tid & 511;
      f16 fa = (f16)h0[(long)b * D_ + 2 * p];
      f16 fb = (f16)h0[(long)b * D_ + 2 * p + 1];
      unsigned u = (unsigned)*(unsigned short*)&fa |
                   ((unsigned)*(unsigned short*)&fb << 16);
      slots[tid] = (u64)u;
    } else {
      slots[tid] = 0xFFFFFFFF00000000ull;  // parity 1 sentinel
    }
  }
}

// ---------------------------------------------------------------- phase 1
// 128x128 tile, 4 waves (2x2), BK=32. A reg-staged from fp32 z (convert inline),
// B (Wz f16) via global_load_lds. 2 barriers per K-step.
__global__ __launch_bounds__(256) void k_gemm_zw(
    const float* __restrict__ zf, const f16* __restrict__ wz16,
    const float* __restrict__ bias, float* __restrict__ out) {
  __shared__ f16 ldsA[8 * 512];
  __shared__ f16 ldsB[8 * 512];
  const int tid = threadIdx.x, lane = tid & 63, w = tid >> 6;
  const int r16 = lane & 15, g8 = lane >> 4;
  const int nt = blockIdx.x & 7, mt = blockIdx.x >> 3;
  const long m0 = (long)mt * 128, n0 = (long)nt * 128;
  const int arow = tid >> 1, kh = (tid & 1) * 16;
  const float* gA = zf + (m0 + arow) * D_ + kh;
  const f16* gB = wz16 + (n0 + r16) * D_ + g8 * 8;
  const int wr = w >> 1, wc = w & 1;
  f32x4 acc[4][4] = {};
  float4 ra[4];
#pragma unroll
  for (int q = 0; q < 4; ++q) ra[q] = *(const float4*)(gA + q * 4);

  for (int ks = 0; ks < 32; ++ks) {
    if (ks) __syncthreads();
#pragma unroll
    for (int c = 0; c < 2; ++c) {
      const int ch = w * 2 + c;
      gload_lds16(gB + (long)ch * 16 * D_ + ks * 32, &ldsB[ch * 512]);
    }
    {
      const int ch = arow >> 4, lr = arow & 15;
#pragma unroll
      for (int hf = 0; hf < 2; ++hf) {
        float4 x = ra[hf * 2], y = ra[hf * 2 + 1];
        f16x8 v = {(f16)x.x, (f16)x.y, (f16)x.z, (f16)x.w,
                   (f16)y.x, (f16)y.y, (f16)y.z, (f16)y.w};
        const int kk = kh + hf * 8;
        *(f16x8*)(&ldsA[ch * 512 + (lr | ((kk >> 3) << 4)) * 8]) = v;
      }
    }
    __syncthreads();
    if (ks < 31) {
#pragma unroll
      for (int q = 0; q < 4; ++q)
        ra[q] = *(const float4*)(gA + (ks + 1) * 32 + q * 4);
    }
    f16x8 af[4], bf[4];
#pragma unroll
    for (int i = 0; i < 4; ++i)
      af[i] = *(const f16x8*)(&ldsA[(wr * 4 + i) * 512 + lane * 8]);
#pragma unroll
    for (int j = 0; j < 4; ++j)
      bf[j] = *(const f16x8*)(&ldsB[(wc * 4 + j) * 512 + lane * 8]);
#pragma unroll
    for (int i = 0; i < 4; ++i)
#pragma unroll
      for (int j = 0; j < 4; ++j)
        acc[i][j] = __builtin_amdgcn_mfma_f32_16x16x32_f16(af[i], bf[j], acc[i][j], 0, 0, 0);
  }

  float bj[4];
#pragma unroll
  for (int j = 0; j < 4; ++j) bj[j] = bias[n0 + wc * 64 + j * 16 + r16];
#pragma unroll
  for (int i = 0; i < 4; ++i) {
    const long mb = m0 + wr * 64 + i * 16 + g8 * 4;
#pragma unroll
    for (int j = 0; j < 4; ++j) {
      const long nn = n0 + wc * 64 + j * 16 + r16;
#pragma unroll
      for (int r = 0; r < 4; ++r)
        out[(mb + r) * D_ + nn] = acc[i][j][r] + bj[j];
    }
  }
}

// ---------------------------------------------------------------- phase 2
// 256 WGs x 256 threads (1/CU). Mapping keeps a group's 16 WGs on one XCD
// under round-robin (perf heuristic only; correctness is placement-free):
//   xcd = bid&7, s = bid>>3, group = xcd*2 + (s&1), rank = s>>1.
// WG handles batches b0..b0+4 (b0 = group*4), cols j0..j0+64 (j0 = rank*64).
// Wave w owns k-quarter [w*256, w*256+256): polls its 4 producers (8 u64/lane),
// stages to its private Hl quarter, MFMAs vs register-resident Wh frags.
// LDS: Hl u32[4][512] swizzled (8 KB) + red f32[16][64][4] (16 KB) = 24 KB.
__global__ __launch_bounds__(256, 1) void k_recur(
    const f16* __restrict__ wh16, u64* slots, const float* __restrict__ z,
    const float* __restrict__ h0, const float* __restrict__ alpha,
    float* __restrict__ out) {
  __shared__ char Hb[8192];
  __shared__ float red[4096];

  const int tid = threadIdx.x, lane = tid & 63, w = tid >> 6;
  const int bid = blockIdx.x;
  const int g = (bid & 7) * 2 + ((bid >> 3) & 1);
  const int rk = bid >> 4;
  const int j0 = rk * 64, b0 = g * 4;

  // ---- register-resident Wh B-frags: wave w, n-tile n, k-step kt ----
  // frag elem: B[col = j0+n*16+(lane&15)][k = w*256 + kt*32 + (lane>>4)*8 + e]
  f16x8 bfr[32];
  {
    const f16* wb = wh16 + (long)(j0 + (lane & 15)) * D_ + w * 256 + (lane >> 4) * 8;
#pragma unroll
    for (int n = 0; n < 4; ++n)
#pragma unroll
      for (int kt = 0; kt < 8; ++kt)
        bfr[n * 8 + kt] = *(const f16x8*)(wb + (long)n * 16 * D_ + kt * 32);
  }

  const int jj = j0 + lane;
  const float lk = 1.0f - alpha[jj];
  float hp = h0[(long)(b0 + w) * D_ + jj];

  const int row = lane & 3, g8 = lane >> 4;
  const int nn = lane >> 4, jc = lane & 15;

  for (int t = 0; t < T_; ++t) {
    const long off = ((long)(b0 + w) * T_ + t) * D_ + jj;
    // prefetch (in flight during poll; consumed in epilogue)
    float A = out[off];
    float Z = z[off];

    // ---- per-wave fence-free tagged poll: 8 u64/lane covering k-quarter w ----
    const u64* cur = slots + (long)(t & 1) * 32768 + (long)b0 * 512 + w * 128;
    u64 vv[8];
    unsigned pend = 0xFFu;
    for (int guard = 0; pend && guard < (1 << 18); ++guard) {
#pragma unroll
      for (int i = 0; i < 8; ++i)
        if (pend & (1u << i)) {
          const int idx = i * 64 + lane;
          vv[i] = __hip_atomic_load(cur + (idx >> 7) * 512 + (idx & 127),
                                    __ATOMIC_RELAXED, __HIP_MEMORY_SCOPE_AGENT);
        }
#pragma unroll
      for (int i = 0; i < 8; ++i)
        if ((pend & (1u << i)) && (unsigned)(vv[i] >> 32) == (unsigned)t)
          pend &= ~(1u << i);
    }

    // ---- stage own quarter (wave-local; no barrier before MFMA) ----
    // u32 payload (b, lp) -> byte w*2048 + b*512 + lp*4, XOR (b&1)<<6
#pragma unroll
    for (int i = 0; i < 8; ++i) {
      const int idx = i * 64 + lane, b = idx >> 7, lp = idx & 127;
      *(unsigned*)(Hb + ((w * 2048 + b * 512 + lp * 4) ^ ((b & 1) << 6))) =
          (unsigned)vv[i];
    }

    // ---- MFMA: 8 kt x 4 n-tiles; af rows 0-3 = batches (4-15 duplicates) ----
    f32x4 acc[4] = {{0,0,0,0},{0,0,0,0},{0,0,0,0},{0,0,0,0}};
#pragma unroll
    for (int kt = 0; kt < 8; ++kt) {
      f16x8 af = *(const f16x8*)(
          Hb + ((w * 2048 + row * 512 + kt * 64 + g8 * 16) ^ ((row & 1) << 6)));
#pragma unroll
      for (int n = 0; n < 4; ++n)
        acc[n] = __builtin_amdgcn_mfma_f32_16x16x32_f16(af, bfr[n * 8 + kt], acc[n], 0, 0, 0);
    }

    // ---- cross-wave k-reduce via LDS ----
#pragma unroll
    for (int n = 0; n < 4; ++n)
      *(f32x4*)(red + ((w * 4 + n) * 64 + lane) * 4) = acc[n];
    __syncthreads();  // B1: partials visible

    // thread (w, lane) owns output (b0+w, jj): n = lane>>4, jc = lane&15
    float pre = 0.f;
#pragma unroll
    for (int wp = 0; wp < 4; ++wp)
      pre += red[(wp * 4 + nn) * 256 + jc * 4 + w];
    const float gg = 1.0f / (1.0f + expf(-(pre + A)));
    const float hn = tanhf(hp * lk + gg * Z);
    out[off] = hn;  // overwrite A slot in place
    hp = hn;

    // ---- publish tagged pairs (even lanes; relaxed agent atomics) ----
    const float q = __shfl_xor(hn, 1);
    if (!(lane & 1)) {
      f16 pa = (f16)hn, pb = (f16)q;
      const unsigned u = (unsigned)*(unsigned short*)&pa |
                         ((unsigned)*(unsigned short*)&pb << 16);
      const u64 val = (((u64)(unsigned)(t + 1)) << 32) | (u64)u;
      __hip_atomic_store(slots + (long)((t + 1) & 1) * 32768 + (long)(b0 + w) * 512 + (jj >> 1),
                         val, __ATOMIC_RELAXED, __HIP_MEMORY_SCOPE_AGENT);
    }
    __syncthreads();  // B2: red reads done before next step's red writes
  }
}

// ---------------------------------------------------------------- launcher
extern "C" void kernel_launch(void* const* d_in, const int* in_sizes, int n_in,
                              void* d_out, int out_size, void* d_ws, size_t ws_size,
                              hipStream_t stream) {
  const float* h_t = (const float*)d_in[0];
  const float* z = (const float*)d_in[1];
  const float* W = (const float*)d_in[2];
  const float* bias = (const float*)d_in[3];
  const float* alpha = (const float*)d_in[4];
  float* out = (float*)d_out;
  char* ws = (char*)d_ws;
  f16* wh16 = (f16*)(ws + WS_WH16);
  f16* wz16 = (f16*)(ws + WS_WZ16);
  u64* slots = (u64*)(ws + WS_SLOTS);
  // requires ws_size >= 4,718,592 bytes

  k_prep<<<dim3(2048), dim3(256), 0, stream>>>(W, h_t, wh16, wz16, slots);
  k_gemm_zw<<<dim3(2048), dim3(256), 0, stream>>>(z, wz16, bias, out);
  k_recur<<<dim3(256), dim3(256), 0, stream>>>(wh16, slots, z, h_t, alpha, out);
}